// Round 10
// baseline (390.083 us; speedup 1.0000x reference)
//
#include <hip/hip_runtime.h>
#include <math.h>

// Problem constants (fixed by reference)
#define BBATCH 16
#define NPC    2048          // points per cloud
#define KNBR   16            // knn k (self appended -> 17 edges)
#define NPTS   (BBATCH*NPC)  // 32768
#define NBLK   256           // 1 block/CU — co-residency trivially guaranteed
#define BUFCAP 512

// One kernel, 256 persistent blocks, each owns 128 points of ONE cloud.
// Block mapping is cloud-major: cloud = bid & 15, slice = bid >> 4, so the
// 16 blocks of a cloud share an XCD under round-robin bid%8 dispatch and the
// cloud's S2/V gather set (~3 MB) stays L2-resident.
//   G: V = x@Wval, A2 = (x@Wdst)@Wattn, S2 = (x@Wsrc)@Wattn  (2 x 64-row tiles)
//      block 0 also: WP2 = Wpos@Wattn, bb = bpos@Wattn + battn
//   K: exact fp64 16-NN for its 128 targets (R7-proven code); nbr in LDS
//   [device barrier — 256 blocks <= 256 CUs => all resident; no deadlock]
//   E: edge aggregate with ONLINE softmax (3 accumulators, no lg/vl arrays ->
//      no spills at the 64-VGPR allocation R9 measured)
__global__ __launch_bounds__(1024, 4) void mega_kernel(
    const float* __restrict__ pos, const float* __restrict__ x,
    const float* __restrict__ Wpos, const float* __restrict__ bpos,
    const float* __restrict__ Wattn, const float* __restrict__ battn,
    const float* __restrict__ Wval, const float* __restrict__ Wsrc,
    const float* __restrict__ Wdst,
    float* __restrict__ A2, float* __restrict__ S2, float* __restrict__ V,
    float* __restrict__ WP2, float* __restrict__ bb,
    unsigned int* __restrict__ bar, float* __restrict__ out) {
  __shared__ __align__(16) char smem[65536];
  int t = threadIdx.x;
  int bid = blockIdx.x;
  int c = t & 63, g = t >> 6;
  int cloud = bid & 15;        // cloud-major: same-cloud blocks share an XCD
  int slice = bid >> 4;        // 0..15: which 128-point slice of the cloud
  int pbase = cloud * NPC + slice * 128;  // first point owned by this block

  // ---------------- Phase G: gemm, 128 rows per block (2 tiles) ----------
  {
    float* R0 = (float*)smem;            // staging: Wdst / Wsrc / x
    float* R1 = (float*)(smem + 16384);  // Hd = Wdst@Wattn
    float* R2 = (float*)(smem + 32768);  // Hs = Wsrc@Wattn
    float* R3 = (float*)(smem + 49152);  // Wattn, then Wval
    float4* R04 = (float4*)R0;
    float4* R34 = (float4*)R3;

    R34[t] = ((const float4*)Wattn)[t];
    R04[t] = ((const float4*)Wdst)[t];
    __syncthreads();
    {
      float a0 = 0, a1 = 0, a2 = 0, a3 = 0;
      for (int k = 0; k < 64; ++k) {
        float w = R3[k * 64 + c];
        a0 += R0[(g * 4 + 0) * 64 + k] * w;
        a1 += R0[(g * 4 + 1) * 64 + k] * w;
        a2 += R0[(g * 4 + 2) * 64 + k] * w;
        a3 += R0[(g * 4 + 3) * 64 + k] * w;
      }
      R1[(g * 4 + 0) * 64 + c] = a0; R1[(g * 4 + 1) * 64 + c] = a1;
      R1[(g * 4 + 2) * 64 + c] = a2; R1[(g * 4 + 3) * 64 + c] = a3;
    }
    __syncthreads();
    R04[t] = ((const float4*)Wsrc)[t];
    __syncthreads();
    {
      float a0 = 0, a1 = 0, a2 = 0, a3 = 0;
      for (int k = 0; k < 64; ++k) {
        float w = R3[k * 64 + c];
        a0 += R0[(g * 4 + 0) * 64 + k] * w;
        a1 += R0[(g * 4 + 1) * 64 + k] * w;
        a2 += R0[(g * 4 + 2) * 64 + k] * w;
        a3 += R0[(g * 4 + 3) * 64 + k] * w;
      }
      R2[(g * 4 + 0) * 64 + c] = a0; R2[(g * 4 + 1) * 64 + c] = a1;
      R2[(g * 4 + 2) * 64 + c] = a2; R2[(g * 4 + 3) * 64 + c] = a3;
    }
    __syncthreads();
    R34[t] = ((const float4*)Wval)[t];
    __syncthreads();

    for (int tile = 0; tile < 2; ++tile) {
      int R = pbase + tile * 64;
      R04[t] = ((const float4*)(x + (size_t)R * 64))[t];
      __syncthreads();
      float v0 = 0, v1 = 0, v2 = 0, v3 = 0;
      float a0 = 0, a1 = 0, a2 = 0, a3 = 0;
      float s0 = 0, s1 = 0, s2 = 0, s3 = 0;
      const float4* xr0 = (const float4*)(R0 + (g * 4 + 0) * 64);
      const float4* xr1 = (const float4*)(R0 + (g * 4 + 1) * 64);
      const float4* xr2 = (const float4*)(R0 + (g * 4 + 2) * 64);
      const float4* xr3 = (const float4*)(R0 + (g * 4 + 3) * 64);
#pragma unroll 4
      for (int k4 = 0; k4 < 16; ++k4) {
        float4 q0 = xr0[k4], q1 = xr1[k4], q2 = xr2[k4], q3 = xr3[k4];
#pragma unroll
        for (int kk = 0; kk < 4; ++kk) {
          int k = k4 * 4 + kk;
          float wv = R3[k * 64 + c];
          float wa = R1[k * 64 + c];
          float ws = R2[k * 64 + c];
          float e0 = (kk == 0) ? q0.x : (kk == 1) ? q0.y : (kk == 2) ? q0.z : q0.w;
          float e1 = (kk == 0) ? q1.x : (kk == 1) ? q1.y : (kk == 2) ? q1.z : q1.w;
          float e2 = (kk == 0) ? q2.x : (kk == 1) ? q2.y : (kk == 2) ? q2.z : q2.w;
          float e3 = (kk == 0) ? q3.x : (kk == 1) ? q3.y : (kk == 2) ? q3.z : q3.w;
          v0 += e0 * wv; v1 += e1 * wv; v2 += e2 * wv; v3 += e3 * wv;
          a0 += e0 * wa; a1 += e1 * wa; a2 += e2 * wa; a3 += e3 * wa;
          s0 += e0 * ws; s1 += e1 * ws; s2 += e2 * ws; s3 += e3 * ws;
        }
      }
      size_t o0 = ((size_t)R + g * 4 + 0) * 64 + c;
      V[o0] = v0; A2[o0] = a0; S2[o0] = s0;
      size_t o1 = o0 + 64;  V[o1] = v1; A2[o1] = a1; S2[o1] = s1;
      size_t o2 = o0 + 128; V[o2] = v2; A2[o2] = a2; S2[o2] = s2;
      size_t o3 = o0 + 192; V[o3] = v3; A2[o3] = a3; S2[o3] = s3;
      __syncthreads();
    }

    if (bid == 0 && t < 64) {  // prep-lite (consumed after the barrier)
      for (int r = 0; r < 3; ++r) {
        float a = 0.f;
        for (int d = 0; d < 64; ++d) a += Wpos[r * 64 + d] * Wattn[d * 64 + t];
        WP2[r * 64 + t] = a;
      }
      float a = battn[t];
      for (int d = 0; d < 64; ++d) a += bpos[d] * Wattn[d * 64 + t];
      bb[t] = a;
    }
  }
  __syncthreads();

  // ---------------- Phase K: knn, 128 targets per block ----------------
  float4* pos4 = (float4*)smem;                            // 32 KB
  unsigned short* buf = (unsigned short*)(smem + 32768);   // 16 KB (16w x 512)
  unsigned short* nbrl = (unsigned short*)(smem + 49152);  // 4 KB (128 x 16)
  const float* pc = pos + (size_t)cloud * NPC * 3;
  for (int p = t; p < NPC; p += 1024)
    pos4[p] = make_float4(pc[3 * p], pc[3 * p + 1], pc[3 * p + 2], 0.f);
  __syncthreads();

  int w = g, lane = c;
  for (int u = 0; u < 8; ++u) {
    int lt = u * 16 + w;  // local target 0..127
    int ti = slice * 128 + lt;  // index within cloud
    float4 tp = pos4[ti];
    float tx = tp.x, ty = tp.y, tz = tp.z;

    // Phase A: fp32 d^2 -> exponent bucket (self lands in bucket 0, kept)
    int bkt[32];
#pragma unroll
    for (int cc = 0; cc < 32; ++cc) {
      int j = cc * 64 + lane;
      float4 q = pos4[j];
      float dx = tx - q.x, dy = ty - q.y, dz = tz - q.z;
      float d2 = dx * dx + dy * dy + dz * dz;
      int b = (int)(__float_as_uint(d2) >> 20) - 896;
      bkt[cc] = max(0, min(255, b));
    }

    // Phase B: smallest T with count(bkt<=T) >= 17 (16 real + self)
    int lo = 0, hi = 255;
    for (int it = 0; it < 8; ++it) {
      int mid = (lo + hi) >> 1;
      int cnt = 0;
#pragma unroll
      for (int cc = 0; cc < 32; ++cc)
        cnt += (int)__popcll(__ballot(bkt[cc] <= mid));
      if (cnt >= 17) hi = mid; else lo = mid + 1;
    }
    int Tp1 = min(hi + 1, 255);

    // Phase C: atomic-free compaction (ballot + mbcnt prefix)
    int base = 0;
#pragma unroll
    for (int cc = 0; cc < 32; ++cc) {
      bool f = (bkt[cc] <= Tp1);
      unsigned long long mm = __ballot(f);
      unsigned int pre = __builtin_amdgcn_mbcnt_hi(
          (unsigned)(mm >> 32), __builtin_amdgcn_mbcnt_lo((unsigned)mm, 0u));
      if (f) {
        int p = base + (int)pre;
        if (p < BUFCAP) buf[w * BUFCAP + p] = (unsigned short)(cc * 64 + lane);
      }
      base += (int)__popcll(mm);
    }
    int n = min(base, BUFCAP);
    double txd = (double)tx, tyd = (double)ty, tzd = (double)tz;

    if (n <= 64) {
      // fp64 exact keys (bit-match numpy f64 ((dx^2+dy^2)+dz^2)), bitonic-64
      unsigned long long gb = 0xFFFFFFFFFFFFFFFFull;
      int gj = 0x40000000 + lane;
      if (lane < n) {
        int j = buf[w * BUFCAP + lane];
        if (j != ti) {
          float4 q = pos4[j];
          double dx = __dsub_rn(txd, (double)q.x);
          double dy = __dsub_rn(tyd, (double)q.y);
          double dz = __dsub_rn(tzd, (double)q.z);
          double d2 = __dadd_rn(__dadd_rn(__dmul_rn(dx, dx), __dmul_rn(dy, dy)),
                                __dmul_rn(dz, dz));
          gb = (unsigned long long)__double_as_longlong(d2);
          gj = j;
        }
      }
      for (int k = 2; k <= 64; k <<= 1) {
        for (int jj = k >> 1; jj > 0; jj >>= 1) {
          unsigned long long ob = __shfl_xor(gb, jj);
          int oj = __shfl_xor(gj, jj);
          bool keepmin = (((lane & k) == 0) == ((lane & jj) == 0));
          bool less = (ob < gb) || (ob == gb && oj < gj);
          if (keepmin == less) { gb = ob; gj = oj; }
        }
      }
      if (lane < KNBR) nbrl[lt * KNBR + lane] = (unsigned short)gj;
    } else {
      // rare fallback: extraction over buffered set (n <= 512)
      unsigned long long kb2[8];
      int id2[8];
#pragma unroll
      for (int r = 0; r < 8; ++r) {
        int e = r * 64 + lane;
        kb2[r] = 0xFFFFFFFFFFFFFFFFull;
        id2[r] = 0x40000000 + e;
        if (e < n) {
          int j = buf[w * BUFCAP + e];
          if (j != ti) {
            float4 q = pos4[j];
            double dx = __dsub_rn(txd, (double)q.x);
            double dy = __dsub_rn(tyd, (double)q.y);
            double dz = __dsub_rn(tzd, (double)q.z);
            double d2 = __dadd_rn(
                __dadd_rn(__dmul_rn(dx, dx), __dmul_rn(dy, dy)),
                __dmul_rn(dz, dz));
            kb2[r] = (unsigned long long)__double_as_longlong(d2);
            id2[r] = j;
          }
        }
      }
      for (int r = 0; r < KNBR; ++r) {
        unsigned long long lb = kb2[0];
        int lj = id2[0];
#pragma unroll
        for (int cc = 1; cc < 8; ++cc)
          if (kb2[cc] < lb || (kb2[cc] == lb && id2[cc] < lj)) {
            lb = kb2[cc]; lj = id2[cc];
          }
        unsigned long long gb2 = lb;
        int gj2 = lj;
#pragma unroll
        for (int d = 32; d >= 1; d >>= 1) {
          unsigned long long ob = __shfl_xor(gb2, d);
          int oj = __shfl_xor(gj2, d);
          if (ob < gb2 || (ob == gb2 && oj < gj2)) { gb2 = ob; gj2 = oj; }
        }
#pragma unroll
        for (int cc = 0; cc < 8; ++cc)
          if (id2[cc] == gj2) kb2[cc] = 0xFFFFFFFFFFFFFFFFull;
        if (lane == 0) nbrl[lt * KNBR + r] = (unsigned short)gj2;
      }
    }
  }

  // ---------------- device barrier (all 256 blocks resident) -------------
  __threadfence();   // release: drain this block's global writes
  __syncthreads();
  if (t == 0) {
    __atomic_fetch_add(bar, 1u, __ATOMIC_ACQ_REL);
    while (__hip_atomic_load(bar, __ATOMIC_ACQUIRE,
                             __HIP_MEMORY_SCOPE_AGENT) < NBLK) {
      __builtin_amdgcn_s_sleep(8);
    }
  }
  __syncthreads();
  __threadfence();   // acquire side

  // ---------------- Phase E: edge aggregate, ONLINE softmax --------------
  {
    float wp0 = WP2[c], wp1 = WP2[64 + c], wp2 = WP2[128 + c], bbc = bb[c];
    float u0 = Wpos[c], u1 = Wpos[64 + c], u2 = Wpos[128 + c], bpc = bpos[c];
    int cloudbase = cloud * NPC;
    for (int r = 0; r < 8; ++r) {
      int lt = w * 8 + r;
      int gi = cloudbase + slice * 128 + lt;
      int ti = slice * 128 + lt;
      float4 pi = pos4[ti];
      float a2v = A2[(size_t)gi * 64 + c];

      float m = -INFINITY, den = 0.f, acc = 0.f;
#pragma unroll
      for (int e = 0; e < 17; ++e) {
        int j = (e < 16) ? (int)nbrl[lt * KNBR + e] : ti;
        float4 q = pos4[j];
        int jg = cloudbase + j;
        float dx = pi.x - q.x, dy = pi.y - q.y, dz = pi.z - q.z;
        float s2 = S2[(size_t)jg * 64 + c];
        float v = V[(size_t)jg * 64 + c];
        float l = a2v - s2 + dx * wp0 + dy * wp1 + dz * wp2 + bbc;
        float vl = v + dx * u0 + dy * u1 + dz * u2 + bpc;
        float nm = fmaxf(m, l);
        float sc = __expf(m - nm);
        float wg = __expf(l - nm);
        den = den * sc + wg;
        acc = acc * sc + wg * vl;
        m = nm;
      }
      out[(size_t)gi * 64 + c] = acc / den;
    }
  }
}

// ---------------------------------------------------------------------------
extern "C" void kernel_launch(void* const* d_in, const int* in_sizes, int n_in,
                              void* d_out, int out_size, void* d_ws, size_t ws_size,
                              hipStream_t stream) {
  const float* x     = (const float*)d_in[0];
  const float* pos   = (const float*)d_in[1];
  // d_in[2] = batch (contiguous equal clouds; unused)
  const float* Wpos  = (const float*)d_in[3];
  const float* bpos  = (const float*)d_in[4];
  const float* Wattn = (const float*)d_in[5];
  const float* battn = (const float*)d_in[6];
  const float* Wval  = (const float*)d_in[7];
  const float* Wsrc  = (const float*)d_in[8];
  const float* Wdst  = (const float*)d_in[9];

  float* ws  = (float*)d_ws;
  float* A2  = ws;                       // 32768*64
  float* S2  = A2 + (size_t)NPTS * 64;   // 32768*64
  float* V   = S2 + (size_t)NPTS * 64;   // 32768*64
  float* WP2 = V + (size_t)NPTS * 64;    // 3*64
  float* bb  = WP2 + 192;                // 64
  unsigned int* bar = (unsigned int*)(bb + 64);  // barrier counter
  float* out = (float*)d_out;

  // d_ws is re-poisoned to 0xAA before every launch -> zero the barrier word
  // in-stream (hipMemsetAsync is graph-capturable).
  hipMemsetAsync((void*)bar, 0, 64, stream);
  mega_kernel<<<NBLK, 1024, 0, stream>>>(
      pos, x, Wpos, bpos, Wattn, battn, Wval, Wsrc, Wdst,
      A2, S2, V, WP2, bb, bar, out);
}

// Round 11
// 269.802 us; speedup vs baseline: 1.4458x; 1.4458x over previous
//
#include <hip/hip_runtime.h>
#include <math.h>

// Problem constants (fixed by reference)
#define BBATCH 16
#define NPC    2048          // points per cloud
#define KNBR   16            // knn k (self appended -> 17 edges)
#define NPTS   (BBATCH*NPC)  // 32768
#define NGEMM  512           // gemm blocks (64 rows each)
#define NKE    512           // knn+edge blocks (64 targets each)
#define BUFCAP 512

// ---------------------------------------------------------------------------
// Launch 1 — gemm family (R7-proven code): 64 rows/block,
//   V = x@Wval, A2 = (x@Wdst)@Wattn, S2 = (x@Wsrc)@Wattn
//   (Hd/Hs chained in-block via LDS). Block NGEMM: WP2/bb prep.
// ---------------------------------------------------------------------------
__global__ __launch_bounds__(1024) void gemm_kernel(
    const float* __restrict__ x,
    const float* __restrict__ Wpos, const float* __restrict__ bpos,
    const float* __restrict__ Wattn, const float* __restrict__ battn,
    const float* __restrict__ Wval, const float* __restrict__ Wsrc,
    const float* __restrict__ Wdst,
    float* __restrict__ A2, float* __restrict__ S2, float* __restrict__ V,
    float* __restrict__ WP2, float* __restrict__ bb) {
  __shared__ __align__(16) float smem[16384];
  int t = threadIdx.x;
  int bid = blockIdx.x;
  int c = t & 63, g = t >> 6;

  if (bid == NGEMM) {  // ---- prep-lite ----
    if (t < 64) {
      for (int r = 0; r < 3; ++r) {
        float a = 0.f;
        for (int d = 0; d < 64; ++d) a += Wpos[r * 64 + d] * Wattn[d * 64 + t];
        WP2[r * 64 + t] = a;
      }
      float a = battn[t];
      for (int d = 0; d < 64; ++d) a += bpos[d] * Wattn[d * 64 + t];
      bb[t] = a;
    }
    return;
  }

  float* R0 = smem;             // staging: Wdst / Wsrc / x
  float* R1 = smem + 4096;      // Hd = Wdst@Wattn
  float* R2 = smem + 8192;      // Hs = Wsrc@Wattn
  float* R3 = smem + 12288;     // Wattn, then Wval
  float4* R04 = (float4*)R0;
  float4* R34 = (float4*)R3;

  R34[t] = ((const float4*)Wattn)[t];
  R04[t] = ((const float4*)Wdst)[t];
  __syncthreads();
  {
    float a0 = 0, a1 = 0, a2 = 0, a3 = 0;
    for (int k = 0; k < 64; ++k) {
      float w = R3[k * 64 + c];
      a0 += R0[(g * 4 + 0) * 64 + k] * w;
      a1 += R0[(g * 4 + 1) * 64 + k] * w;
      a2 += R0[(g * 4 + 2) * 64 + k] * w;
      a3 += R0[(g * 4 + 3) * 64 + k] * w;
    }
    R1[(g * 4 + 0) * 64 + c] = a0; R1[(g * 4 + 1) * 64 + c] = a1;
    R1[(g * 4 + 2) * 64 + c] = a2; R1[(g * 4 + 3) * 64 + c] = a3;
  }
  __syncthreads();
  R04[t] = ((const float4*)Wsrc)[t];
  __syncthreads();
  {
    float a0 = 0, a1 = 0, a2 = 0, a3 = 0;
    for (int k = 0; k < 64; ++k) {
      float w = R3[k * 64 + c];
      a0 += R0[(g * 4 + 0) * 64 + k] * w;
      a1 += R0[(g * 4 + 1) * 64 + k] * w;
      a2 += R0[(g * 4 + 2) * 64 + k] * w;
      a3 += R0[(g * 4 + 3) * 64 + k] * w;
    }
    R2[(g * 4 + 0) * 64 + c] = a0; R2[(g * 4 + 1) * 64 + c] = a1;
    R2[(g * 4 + 2) * 64 + c] = a2; R2[(g * 4 + 3) * 64 + c] = a3;
  }
  __syncthreads();
  R34[t] = ((const float4*)Wval)[t];
  R04[t] = ((const float4*)(x + (size_t)bid * 64 * 64))[t];
  __syncthreads();

  float v0 = 0, v1 = 0, v2 = 0, v3 = 0;
  float a0 = 0, a1 = 0, a2 = 0, a3 = 0;
  float s0 = 0, s1 = 0, s2 = 0, s3 = 0;
  const float4* xr0 = (const float4*)(R0 + (g * 4 + 0) * 64);
  const float4* xr1 = (const float4*)(R0 + (g * 4 + 1) * 64);
  const float4* xr2 = (const float4*)(R0 + (g * 4 + 2) * 64);
  const float4* xr3 = (const float4*)(R0 + (g * 4 + 3) * 64);
#pragma unroll 4
  for (int k4 = 0; k4 < 16; ++k4) {
    float4 q0 = xr0[k4], q1 = xr1[k4], q2 = xr2[k4], q3 = xr3[k4];
#pragma unroll
    for (int kk = 0; kk < 4; ++kk) {
      int k = k4 * 4 + kk;
      float wv = R3[k * 64 + c];
      float wa = R1[k * 64 + c];
      float ws = R2[k * 64 + c];
      float e0 = (kk == 0) ? q0.x : (kk == 1) ? q0.y : (kk == 2) ? q0.z : q0.w;
      float e1 = (kk == 0) ? q1.x : (kk == 1) ? q1.y : (kk == 2) ? q1.z : q1.w;
      float e2 = (kk == 0) ? q2.x : (kk == 1) ? q2.y : (kk == 2) ? q2.z : q2.w;
      float e3 = (kk == 0) ? q3.x : (kk == 1) ? q3.y : (kk == 2) ? q3.z : q3.w;
      v0 += e0 * wv; v1 += e1 * wv; v2 += e2 * wv; v3 += e3 * wv;
      a0 += e0 * wa; a1 += e1 * wa; a2 += e2 * wa; a3 += e3 * wa;
      s0 += e0 * ws; s1 += e1 * ws; s2 += e2 * ws; s3 += e3 * ws;
    }
  }
  size_t o0 = ((size_t)bid * 64 + g * 4 + 0) * 64 + c;
  V[o0] = v0; A2[o0] = a0; S2[o0] = s0;
  size_t o1 = o0 + 64;  V[o1] = v1; A2[o1] = a1; S2[o1] = s1;
  size_t o2 = o0 + 128; V[o2] = v2; A2[o2] = a2; S2[o2] = s2;
  size_t o3 = o0 + 192; V[o3] = v3; A2[o3] = a3; S2[o3] = s3;
}

// ---------------------------------------------------------------------------
// Launch 2 — knn+edge fused, 64 targets per block, cloud-major mapping:
// cloud = bid & 15 -> all 32 blocks of a cloud land on XCD (cloud%8) under
// round-robin dispatch; per-XCD working set = 2 clouds x 1.5 MB < 4 MB L2.
// knn: R7-proven exact fp64 16-NN (bucket prefilter + bitonic re-rank),
// nbr kept in LDS. edge: online softmax (R10-proven absmax-safe), pos/nbr
// from LDS, S2/V gathers from L2.
// ---------------------------------------------------------------------------
__global__ __launch_bounds__(1024) void knn_edge_kernel(
    const float* __restrict__ pos,
    const float* __restrict__ A2, const float* __restrict__ S2,
    const float* __restrict__ V, const float* __restrict__ WP2,
    const float* __restrict__ bbv, const float* __restrict__ Wpos,
    const float* __restrict__ bpos, float* __restrict__ out) {
  __shared__ __align__(16) char smem[51200];
  float4* pos4 = (float4*)smem;                            // 32 KB
  unsigned short* buf = (unsigned short*)(smem + 32768);   // 16 KB (16w x 512)
  unsigned short* nbrl = (unsigned short*)(smem + 49152);  // 2 KB (64 x 16)

  int t = threadIdx.x;
  int bid = blockIdx.x;
  int cloud = bid & 15;   // cloud-major: same-cloud blocks share an XCD
  int slice = bid >> 4;   // 0..31: which 64-target slice of the cloud
  const float* pc = pos + (size_t)cloud * NPC * 3;
  for (int p = t; p < NPC; p += 1024)
    pos4[p] = make_float4(pc[3 * p], pc[3 * p + 1], pc[3 * p + 2], 0.f);
  __syncthreads();

  int w = t >> 6, lane = t & 63;
  for (int u = 0; u < 4; ++u) {
    int lt = u * 16 + w;        // local target 0..63
    int ti = slice * 64 + lt;   // index within cloud
    float4 tp = pos4[ti];
    float tx = tp.x, ty = tp.y, tz = tp.z;

    // Phase A: fp32 d^2 -> exponent bucket (self lands in bucket 0, kept)
    int bkt[32];
#pragma unroll
    for (int cc = 0; cc < 32; ++cc) {
      int j = cc * 64 + lane;
      float4 q = pos4[j];
      float dx = tx - q.x, dy = ty - q.y, dz = tz - q.z;
      float d2 = dx * dx + dy * dy + dz * dz;
      int b = (int)(__float_as_uint(d2) >> 20) - 896;
      bkt[cc] = max(0, min(255, b));
    }

    // Phase B: smallest T with count(bkt<=T) >= 17 (16 real + self)
    int lo = 0, hi = 255;
    for (int it = 0; it < 8; ++it) {
      int mid = (lo + hi) >> 1;
      int cnt = 0;
#pragma unroll
      for (int cc = 0; cc < 32; ++cc)
        cnt += (int)__popcll(__ballot(bkt[cc] <= mid));
      if (cnt >= 17) hi = mid; else lo = mid + 1;
    }
    int Tp1 = min(hi + 1, 255);

    // Phase C: atomic-free compaction (ballot + mbcnt prefix)
    int base = 0;
#pragma unroll
    for (int cc = 0; cc < 32; ++cc) {
      bool f = (bkt[cc] <= Tp1);
      unsigned long long mm = __ballot(f);
      unsigned int pre = __builtin_amdgcn_mbcnt_hi(
          (unsigned)(mm >> 32), __builtin_amdgcn_mbcnt_lo((unsigned)mm, 0u));
      if (f) {
        int p = base + (int)pre;
        if (p < BUFCAP) buf[w * BUFCAP + p] = (unsigned short)(cc * 64 + lane);
      }
      base += (int)__popcll(mm);
    }
    int n = min(base, BUFCAP);
    double txd = (double)tx, tyd = (double)ty, tzd = (double)tz;

    if (n <= 64) {
      // fp64 exact keys (bit-match numpy f64 ((dx^2+dy^2)+dz^2)), bitonic-64
      unsigned long long gb = 0xFFFFFFFFFFFFFFFFull;
      int gj = 0x40000000 + lane;
      if (lane < n) {
        int j = buf[w * BUFCAP + lane];
        if (j != ti) {
          float4 q = pos4[j];
          double dx = __dsub_rn(txd, (double)q.x);
          double dy = __dsub_rn(tyd, (double)q.y);
          double dz = __dsub_rn(tzd, (double)q.z);
          double d2 = __dadd_rn(__dadd_rn(__dmul_rn(dx, dx), __dmul_rn(dy, dy)),
                                __dmul_rn(dz, dz));
          gb = (unsigned long long)__double_as_longlong(d2);
          gj = j;
        }
      }
      for (int k = 2; k <= 64; k <<= 1) {
        for (int jj = k >> 1; jj > 0; jj >>= 1) {
          unsigned long long ob = __shfl_xor(gb, jj);
          int oj = __shfl_xor(gj, jj);
          bool keepmin = (((lane & k) == 0) == ((lane & jj) == 0));
          bool less = (ob < gb) || (ob == gb && oj < gj);
          if (keepmin == less) { gb = ob; gj = oj; }
        }
      }
      if (lane < KNBR) nbrl[lt * KNBR + lane] = (unsigned short)gj;
    } else {
      // rare fallback: extraction over buffered set (n <= 512)
      unsigned long long kb2[8];
      int id2[8];
#pragma unroll
      for (int r = 0; r < 8; ++r) {
        int e = r * 64 + lane;
        kb2[r] = 0xFFFFFFFFFFFFFFFFull;
        id2[r] = 0x40000000 + e;
        if (e < n) {
          int j = buf[w * BUFCAP + e];
          if (j != ti) {
            float4 q = pos4[j];
            double dx = __dsub_rn(txd, (double)q.x);
            double dy = __dsub_rn(tyd, (double)q.y);
            double dz = __dsub_rn(tzd, (double)q.z);
            double d2 = __dadd_rn(
                __dadd_rn(__dmul_rn(dx, dx), __dmul_rn(dy, dy)),
                __dmul_rn(dz, dz));
            kb2[r] = (unsigned long long)__double_as_longlong(d2);
            id2[r] = j;
          }
        }
      }
      for (int r = 0; r < KNBR; ++r) {
        unsigned long long lb = kb2[0];
        int lj = id2[0];
#pragma unroll
        for (int cc = 1; cc < 8; ++cc)
          if (kb2[cc] < lb || (kb2[cc] == lb && id2[cc] < lj)) {
            lb = kb2[cc]; lj = id2[cc];
          }
        unsigned long long gb2 = lb;
        int gj2 = lj;
#pragma unroll
        for (int d = 32; d >= 1; d >>= 1) {
          unsigned long long ob = __shfl_xor(gb2, d);
          int oj = __shfl_xor(gj2, d);
          if (ob < gb2 || (ob == gb2 && oj < gj2)) { gb2 = ob; gj2 = oj; }
        }
#pragma unroll
        for (int cc = 0; cc < 8; ++cc)
          if (id2[cc] == gj2) kb2[cc] = 0xFFFFFFFFFFFFFFFFull;
        if (lane == 0) nbrl[lt * KNBR + r] = (unsigned short)gj2;
      }
    }
  }
  __syncthreads();

  // ---- edge phase: online softmax, 4 targets per wave ----
  {
    int c = lane;
    float wp0 = WP2[c], wp1 = WP2[64 + c], wp2 = WP2[128 + c], bbc = bbv[c];
    float u0 = Wpos[c], u1 = Wpos[64 + c], u2 = Wpos[128 + c], bpc = bpos[c];
    int cloudbase = cloud * NPC;
    for (int r = 0; r < 4; ++r) {
      int lt = w * 4 + r;
      int ti = slice * 64 + lt;
      int gi = cloudbase + ti;
      float4 pi = pos4[ti];
      float a2v = A2[(size_t)gi * 64 + c];

      float m = -INFINITY, den = 0.f, acc = 0.f;
#pragma unroll
      for (int e = 0; e < 17; ++e) {
        int j = (e < 16) ? (int)nbrl[lt * KNBR + e] : ti;
        float4 q = pos4[j];
        int jg = cloudbase + j;
        float dx = pi.x - q.x, dy = pi.y - q.y, dz = pi.z - q.z;
        float s2 = S2[(size_t)jg * 64 + c];
        float v = V[(size_t)jg * 64 + c];
        float l = a2v - s2 + dx * wp0 + dy * wp1 + dz * wp2 + bbc;
        float vl = v + dx * u0 + dy * u1 + dz * u2 + bpc;
        float nm = fmaxf(m, l);
        float sc = __expf(m - nm);
        float wg = __expf(l - nm);
        den = den * sc + wg;
        acc = acc * sc + wg * vl;
        m = nm;
      }
      out[(size_t)gi * 64 + c] = acc / den;
    }
  }
}

// ---------------------------------------------------------------------------
extern "C" void kernel_launch(void* const* d_in, const int* in_sizes, int n_in,
                              void* d_out, int out_size, void* d_ws, size_t ws_size,
                              hipStream_t stream) {
  const float* x     = (const float*)d_in[0];
  const float* pos   = (const float*)d_in[1];
  // d_in[2] = batch (contiguous equal clouds; unused)
  const float* Wpos  = (const float*)d_in[3];
  const float* bpos  = (const float*)d_in[4];
  const float* Wattn = (const float*)d_in[5];
  const float* battn = (const float*)d_in[6];
  const float* Wval  = (const float*)d_in[7];
  const float* Wsrc  = (const float*)d_in[8];
  const float* Wdst  = (const float*)d_in[9];

  float* ws  = (float*)d_ws;
  float* A2  = ws;                       // 32768*64
  float* S2  = A2 + (size_t)NPTS * 64;   // 32768*64
  float* V   = S2 + (size_t)NPTS * 64;   // 32768*64
  float* WP2 = V + (size_t)NPTS * 64;    // 3*64
  float* bb  = WP2 + 192;                // 64
  float* out = (float*)d_out;

  gemm_kernel<<<NGEMM + 1, 1024, 0, stream>>>(
      x, Wpos, bpos, Wattn, battn, Wval, Wsrc, Wdst, A2, S2, V, WP2, bb);
  knn_edge_kernel<<<NKE, 1024, 0, stream>>>(
      pos, A2, S2, V, WP2, bb, Wpos, bpos, out);
}